// Round 1
// baseline (177.012 us; speedup 1.0000x reference)
//
#include <hip/hip_runtime.h>
#include <hip/hip_bf16.h>

typedef float f32x4 __attribute__((ext_vector_type(4)));
typedef short s16x8 __attribute__((ext_vector_type(8)));
typedef short s16x4 __attribute__((ext_vector_type(4)));

#define NB  4
#define NTQ 128
#define NTK 512
#define NH  1024

__device__ __forceinline__ unsigned short f2bf(float x) {
    unsigned u = __builtin_bit_cast(unsigned, x);
    u += 0x7FFFu + ((u >> 16) & 1u);          // round-to-nearest-even
    return (unsigned short)(u >> 16);
}

#define ASTR 40   // LDS row stride in shorts (80 B): 16B-aligned rows, ~2-way banks

// blocks [0,32):   wq_out[512][1024] = Q[512][1024] @ Wq + bq   (row-major)
// blocks [32,160): uhT[b][h][k]      = (K[2048][1024] @ Wk) transposed per batch
__global__ __launch_bounds__(256) void fused_gemm(
    const float* __restrict__ Q, const float* __restrict__ Kmat,
    const float* __restrict__ Wq, const float* __restrict__ bq,
    const float* __restrict__ Wk,
    float* __restrict__ wq_out, float* __restrict__ uhT)
{
    __shared__ short As[128][ASTR];   // As[m][k] bf16 bits
    __shared__ short Bs[128][ASTR];   // Bs[n][k] bf16 bits (B staged transposed)
    const int t  = threadIdx.x;
    const int bx = blockIdx.x;
    const bool g1 = bx < 32;
    const float* A; const float* Bg; int mt, nt;
    if (g1) { A = Q;    Bg = Wq; mt = bx >> 3;        nt = bx & 7; }
    else    { A = Kmat; Bg = Wk; mt = (bx - 32) >> 3; nt = (bx - 32) & 7; }
    const int m0 = mt * 128, n0 = nt * 128;

    f32x4 acc[4][4];
    #pragma unroll
    for (int i = 0; i < 4; ++i)
        #pragma unroll
        for (int j = 0; j < 4; ++j) acc[i][j] = f32x4{0.f, 0.f, 0.f, 0.f};

    const int lane = t & 63, wid = t >> 6;
    const int wr = wid >> 1, wc = wid & 1;          // 2x2 waves, 64x64 each
    const int fr = lane & 15, fk = (lane >> 4) * 8; // frag row/col + k-offset

    for (int k0 = 0; k0 < 1024; k0 += 32) {
        __syncthreads();
        {   // stage A tile 128x32 (coalesced float4 rows), convert to bf16
            const int rb = t >> 3, colg = (t & 7) * 4;
            #pragma unroll
            for (int rr = 0; rr < 4; ++rr) {
                const int row = rb + rr * 32;
                const float4 av = *(const float4*)&A[(size_t)(m0 + row) * 1024 + k0 + colg];
                s16x4 pv = { (short)f2bf(av.x), (short)f2bf(av.y),
                             (short)f2bf(av.z), (short)f2bf(av.w) };
                *(s16x4*)&As[row][colg] = pv;
            }
        }
        {   // stage B tile 32x128 -> Bs[n][k]: 4 k-strided scalar loads (lane-coalesced in n)
            const int n = t & 127, kq = (t >> 7) * 4;
            #pragma unroll
            for (int rr = 0; rr < 4; ++rr) {
                const int ks = kq + rr * 8;
                const float* bp = &Bg[(size_t)(k0 + ks) * 1024 + n0 + n];
                const float x0 = bp[0], x1 = bp[1024], x2 = bp[2048], x3 = bp[3072];
                s16x4 pv = { (short)f2bf(x0), (short)f2bf(x1),
                             (short)f2bf(x2), (short)f2bf(x3) };
                *(s16x4*)&Bs[n][ks] = pv;
            }
        }
        __syncthreads();
        s16x8 af[4], bfv[4];
        #pragma unroll
        for (int mi = 0; mi < 4; ++mi)
            af[mi] = *(const s16x8*)&As[wr * 64 + mi * 16 + fr][fk];
        #pragma unroll
        for (int ni = 0; ni < 4; ++ni)
            bfv[ni] = *(const s16x8*)&Bs[wc * 64 + ni * 16 + fr][fk];
        #pragma unroll
        for (int mi = 0; mi < 4; ++mi)
            #pragma unroll
            for (int ni = 0; ni < 4; ++ni)
                acc[mi][ni] = __builtin_amdgcn_mfma_f32_16x16x32_bf16(
                                  af[mi], bfv[ni], acc[mi][ni], 0, 0, 0);
    }

    // D layout (verified m89): col = lane&15, row = (lane>>4)*4 + reg
    const int row0 = (lane >> 4) * 4;
    if (g1) {
        #pragma unroll
        for (int ni = 0; ni < 4; ++ni) {
            const int n = n0 + wc * 64 + ni * 16 + fr;
            const float bias = bq[n];
            #pragma unroll
            for (int mi = 0; mi < 4; ++mi) {
                const int m = m0 + wr * 64 + mi * 16 + row0;
                #pragma unroll
                for (int j = 0; j < 4; ++j)
                    wq_out[(size_t)(m + j) * 1024 + n] = acc[mi][ni][j] + bias;
            }
        }
    } else {
        #pragma unroll
        for (int mi = 0; mi < 4; ++mi) {
            const int m = m0 + wr * 64 + mi * 16 + row0;
            const int b = m >> 9, kk = m & 511;      // 4 consecutive kk -> float4 store
            #pragma unroll
            for (int ni = 0; ni < 4; ++ni) {
                const int n = n0 + wc * 64 + ni * 16 + fr;
                *(f32x4*)&uhT[((size_t)b * 1024 + n) * 512 + kk] = acc[mi][ni];
            }
        }
    }
}

// One block per (b,q): 512 threads = one k per thread.
// score[k] = sum_h tanh(wq[h]+uh[k][h]) * v[h];  tanh(x) = 1 - 2/(exp(2x)+1)
__global__ __launch_bounds__(512) void attn_kernel(
    const float* __restrict__ uhT, const float* __restrict__ wqm,
    const float* __restrict__ v, const float* __restrict__ value,
    float* __restrict__ out)
{
    __shared__ float2 s_wv[1024];   // {2*wq[h], v[h]}
    __shared__ float  s_attn[512];
    __shared__ float  s_red[16];
    const int t   = threadIdx.x;
    const int bqi = blockIdx.x;         // b*128 + q
    const int b   = bqi >> 7;

    const float* wrow = wqm + (size_t)bqi * 1024;
    for (int h = t; h < 1024; h += 512)
        s_wv[h] = make_float2(2.0f * wrow[h], v[h]);
    __syncthreads();

    const float* up = uhT + (size_t)b * 1024 * 512 + t;   // uhT[b][h][k=t]
    float score = 0.f;
    #pragma unroll 8
    for (int h = 0; h < 1024; ++h) {
        const float u   = up[(size_t)h * 512];            // coalesced across lanes
        const float2 wv = s_wv[h];                        // LDS broadcast
        const float arg = __builtin_fmaf(2.0f, u, wv.x);  // 2*(wq+uh)
        const float e   = __expf(arg);
        const float r   = __builtin_amdgcn_rcpf(e + 1.0f);
        const float th  = __builtin_fmaf(-2.0f, r, 1.0f); // tanh
        score = __builtin_fmaf(wv.y, th, score);
    }

    // block softmax over 512 values (one per thread)
    const int lane = t & 63, wid = t >> 6;
    float m = score;
    #pragma unroll
    for (int off = 32; off > 0; off >>= 1)
        m = fmaxf(m, __shfl_xor(m, off, 64));
    if (lane == 0) s_red[wid] = m;
    __syncthreads();
    if (t < 64) {
        float mm = (t < 8) ? s_red[t] : -3.0e38f;
        #pragma unroll
        for (int off = 4; off > 0; off >>= 1)
            mm = fmaxf(mm, __shfl_xor(mm, off, 64));
        if (t == 0) s_red[8] = mm;
    }
    __syncthreads();
    const float gmax = s_red[8];
    const float p = __expf(score - gmax);
    float s = p;
    #pragma unroll
    for (int off = 32; off > 0; off >>= 1)
        s += __shfl_xor(s, off, 64);
    if (lane == 0) s_red[wid] = s;
    __syncthreads();
    if (t < 64) {
        float ss = (t < 8) ? s_red[t] : 0.f;
        #pragma unroll
        for (int off = 4; off > 0; off >>= 1)
            ss += __shfl_xor(ss, off, 64);
        if (t == 0) s_red[9] = ss;
    }
    __syncthreads();
    const float inv  = 1.0f / s_red[9];
    const float attn = p * inv;
    s_attn[t] = attn;
    out[(size_t)(NB * NTQ * NH) + (size_t)bqi * 512 + t] = attn;  // attn output
    __syncthreads();

    // PV: h[b,q,d] = sum_k attn[k] * value[b,k,d]; thread covers d = 2t, 2t+1
    const float* vb = value + (size_t)b * 512 * 1024;
    const int d0 = t * 2;
    float a0 = 0.f, a1 = 0.f;
    #pragma unroll 4
    for (int k = 0; k < 512; ++k) {
        const float  ak = s_attn[k];
        const float2 vv = *(const float2*)&vb[(size_t)k * 1024 + d0];
        a0 = __builtin_fmaf(ak, vv.x, a0);
        a1 = __builtin_fmaf(ak, vv.y, a1);
    }
    *(float2*)&out[(size_t)bqi * 1024 + d0] = make_float2(a0, a1);
}

extern "C" void kernel_launch(void* const* d_in, const int* in_sizes, int n_in,
                              void* d_out, int out_size, void* d_ws, size_t ws_size,
                              hipStream_t stream)
{
    const float* query = (const float*)d_in[0];
    const float* key   = (const float*)d_in[1];
    const float* value = (const float*)d_in[2];
    const float* Wq    = (const float*)d_in[3];
    const float* bq    = (const float*)d_in[4];
    const float* Wk    = (const float*)d_in[5];
    const float* v     = (const float*)d_in[6];
    float* out = (float*)d_out;

    float* ws_wq  = (float*)d_ws;            // 512*1024 f32 = 2 MB
    float* ws_uhT = ws_wq + 512 * 1024;      // 4*1024*512 f32 = 8 MB

    fused_gemm<<<dim3(160), dim3(256), 0, stream>>>(query, key, Wq, bq, Wk, ws_wq, ws_uhT);
    attn_kernel<<<dim3(512), dim3(512), 0, stream>>>(ws_uhT, ws_wq, v, value, out);
}

// Round 2
// 129.175 us; speedup vs baseline: 1.3703x; 1.3703x over previous
//
#include <hip/hip_runtime.h>
#include <hip/hip_bf16.h>

typedef float f32x4 __attribute__((ext_vector_type(4)));
typedef short s16x8 __attribute__((ext_vector_type(8)));
typedef short s16x4 __attribute__((ext_vector_type(4)));

#define NB  4
#define NTQ 128
#define NTK 512
#define NH  1024

__device__ __forceinline__ unsigned short f2bf(float x) {
    unsigned u = __builtin_bit_cast(unsigned, x);
    u += 0x7FFFu + ((u >> 16) & 1u);          // round-to-nearest-even
    return (unsigned short)(u >> 16);
}

#define ASTR 40   // LDS row stride in shorts (80 B)
#define K2E  2.8853900817779268f   // 2*log2(e): exp2(K2E*x) = e^{2x}

// blocks [0,32):   Ea[512][1024] = exp(2*(Q@Wq + bq))        (row-major, row = b*128+q)
// blocks [32,160): EbT[b][h][k]  = exp(2*(K@Wk)) transposed per batch
__global__ __launch_bounds__(256) void fused_gemm(
    const float* __restrict__ Q, const float* __restrict__ Kmat,
    const float* __restrict__ Wq, const float* __restrict__ bq,
    const float* __restrict__ Wk,
    float* __restrict__ Ea_out, float* __restrict__ EbT)
{
    __shared__ short As[128][ASTR];   // As[m][k] bf16 bits
    __shared__ short Bs[128][ASTR];   // Bs[n][k] bf16 bits
    const int t  = threadIdx.x;
    const int bx = blockIdx.x;
    const bool g1 = bx < 32;
    const float* A; const float* Bg; int mt, nt;
    if (g1) { A = Q;    Bg = Wq; mt = bx >> 3;        nt = bx & 7; }
    else    { A = Kmat; Bg = Wk; mt = (bx - 32) >> 3; nt = (bx - 32) & 7; }
    const int m0 = mt * 128, n0 = nt * 128;

    f32x4 acc[4][4];
    #pragma unroll
    for (int i = 0; i < 4; ++i)
        #pragma unroll
        for (int j = 0; j < 4; ++j) acc[i][j] = f32x4{0.f, 0.f, 0.f, 0.f};

    const int lane = t & 63, wid = t >> 6;
    const int wr = wid >> 1, wc = wid & 1;          // 2x2 waves, 64x64 each
    const int fr = lane & 15, fk = (lane >> 4) * 8;

    for (int k0 = 0; k0 < 1024; k0 += 32) {
        __syncthreads();
        {   // stage A tile 128x32
            const int rb = t >> 3, colg = (t & 7) * 4;
            #pragma unroll
            for (int rr = 0; rr < 4; ++rr) {
                const int row = rb + rr * 32;
                const float4 av = *(const float4*)&A[(size_t)(m0 + row) * 1024 + k0 + colg];
                s16x4 pv = { (short)f2bf(av.x), (short)f2bf(av.y),
                             (short)f2bf(av.z), (short)f2bf(av.w) };
                *(s16x4*)&As[row][colg] = pv;
            }
        }
        {   // stage B tile 32x128 -> Bs[n][k]
            const int n = t & 127, kq = (t >> 7) * 4;
            #pragma unroll
            for (int rr = 0; rr < 4; ++rr) {
                const int ks = kq + rr * 8;
                const float* bp = &Bg[(size_t)(k0 + ks) * 1024 + n0 + n];
                const float x0 = bp[0], x1 = bp[1024], x2 = bp[2048], x3 = bp[3072];
                s16x4 pv = { (short)f2bf(x0), (short)f2bf(x1),
                             (short)f2bf(x2), (short)f2bf(x3) };
                *(s16x4*)&Bs[n][ks] = pv;
            }
        }
        __syncthreads();
        s16x8 af[4], bfv[4];
        #pragma unroll
        for (int mi = 0; mi < 4; ++mi)
            af[mi] = *(const s16x8*)&As[wr * 64 + mi * 16 + fr][fk];
        #pragma unroll
        for (int ni = 0; ni < 4; ++ni)
            bfv[ni] = *(const s16x8*)&Bs[wc * 64 + ni * 16 + fr][fk];
        #pragma unroll
        for (int mi = 0; mi < 4; ++mi)
            #pragma unroll
            for (int ni = 0; ni < 4; ++ni)
                acc[mi][ni] = __builtin_amdgcn_mfma_f32_16x16x32_bf16(
                                  af[mi], bfv[ni], acc[mi][ni], 0, 0, 0);
    }

    // D layout: col = lane&15, row = (lane>>4)*4 + reg
    const int row0 = (lane >> 4) * 4;
    if (g1) {
        #pragma unroll
        for (int ni = 0; ni < 4; ++ni) {
            const int n = n0 + wc * 64 + ni * 16 + fr;
            const float bias = bq[n];
            #pragma unroll
            for (int mi = 0; mi < 4; ++mi) {
                const int m = m0 + wr * 64 + mi * 16 + row0;
                #pragma unroll
                for (int j = 0; j < 4; ++j)
                    Ea_out[(size_t)(m + j) * 1024 + n] =
                        __builtin_amdgcn_exp2f(K2E * (acc[mi][ni][j] + bias));
            }
        }
    } else {
        #pragma unroll
        for (int mi = 0; mi < 4; ++mi) {
            const int m = m0 + wr * 64 + mi * 16 + row0;
            const int b = m >> 9, kk = m & 511;
            #pragma unroll
            for (int ni = 0; ni < 4; ++ni) {
                const int n = n0 + wc * 64 + ni * 16 + fr;
                f32x4 ev;
                #pragma unroll
                for (int j = 0; j < 4; ++j)
                    ev[j] = __builtin_amdgcn_exp2f(K2E * acc[mi][ni][j]);
                *(f32x4*)&EbT[((size_t)b * 1024 + n) * 512 + kk] = ev;
            }
        }
    }
}

// scores stage: tanh(a+b) = 1 - 2/(1+Ea*Eb); the "1-" and Sum(v) cancel in softmax.
// partial[bqi][hq][k] = sum_{h in quarter} v[h] * rcp(1 + Ea[bqi][h]*Eb[b][h][k])
// grid: ((b*64+qpair)*4 + hq), 512 threads = k
__global__ __launch_bounds__(512) void scores_partial(
    const float* __restrict__ EbT, const float* __restrict__ Ea,
    const float* __restrict__ v, float* __restrict__ partial)
{
    __shared__ float4 s_ev[256];   // {Ea_q0[h], Ea_q1[h], v[h], 0}
    const int t   = threadIdx.x;
    const int bx  = blockIdx.x;
    const int hq  = bx & 3;
    const int bqp = bx >> 2;           // b*64 + qpair
    const int b   = bqp >> 6;
    const int qp  = bqp & 63;
    const int bq0 = b * 128 + qp * 2;  // global (b,q) row of q0
    const int h0  = hq * 256;

    if (t < 256) {
        const int h = h0 + t;
        const float e0 = Ea[(size_t)bq0 * 1024 + h];
        const float e1 = Ea[(size_t)(bq0 + 1) * 1024 + h];
        s_ev[t] = make_float4(e0, e1, v[h], 0.f);
    }
    __syncthreads();

    const float* up = EbT + ((size_t)b * 1024 + h0) * 512 + t;
    float a0 = 0.f, a1 = 0.f;
    #pragma unroll 8
    for (int hh = 0; hh < 256; ++hh) {
        const float  eb = up[(size_t)hh * 512];          // coalesced across lanes
        const float4 ev = s_ev[hh];                      // LDS broadcast
        const float r0 = __builtin_amdgcn_rcpf(__builtin_fmaf(ev.x, eb, 1.0f));
        const float r1 = __builtin_amdgcn_rcpf(__builtin_fmaf(ev.y, eb, 1.0f));
        a0 = __builtin_fmaf(ev.z, r0, a0);
        a1 = __builtin_fmaf(ev.z, r1, a1);
    }
    partial[((size_t)bq0 * 4 + hq) * 512 + t]       = a0;
    partial[((size_t)(bq0 + 1) * 4 + hq) * 512 + t] = a1;
}

// softmax over k: attn = softmax_k(-2 * sum_hq partial). One block per (b,q).
__global__ __launch_bounds__(512) void softmax_kernel(
    const float* __restrict__ partial, float* __restrict__ attn_out)
{
    __shared__ float s_red[16];
    const int t = threadIdx.x, bqi = blockIdx.x;
    const float* p = partial + (size_t)bqi * 2048;
    const float z = -2.0f * (p[t] + p[512 + t] + p[1024 + t] + p[1536 + t]);

    const int lane = t & 63, wid = t >> 6;
    float m = z;
    #pragma unroll
    for (int off = 32; off > 0; off >>= 1)
        m = fmaxf(m, __shfl_xor(m, off, 64));
    if (lane == 0) s_red[wid] = m;
    __syncthreads();
    if (t < 64) {
        float mm = (t < 8) ? s_red[t] : -3.0e38f;
        #pragma unroll
        for (int off = 4; off > 0; off >>= 1)
            mm = fmaxf(mm, __shfl_xor(mm, off, 64));
        if (t == 0) s_red[8] = mm;
    }
    __syncthreads();
    const float pr = __expf(z - s_red[8]);
    float s = pr;
    #pragma unroll
    for (int off = 32; off > 0; off >>= 1)
        s += __shfl_xor(s, off, 64);
    if (lane == 0) s_red[wid] = s;
    __syncthreads();
    if (t < 64) {
        float ss = (t < 8) ? s_red[t] : 0.f;
        #pragma unroll
        for (int off = 4; off > 0; off >>= 1)
            ss += __shfl_xor(ss, off, 64);
        if (t == 0) s_red[9] = ss;
    }
    __syncthreads();
    attn_out[(size_t)bqi * 512 + t] = pr * (1.0f / s_red[9]);
}

// PV: h[bq][d] = sum_k attn[bq][k] * value[b][k][d]
// grid: ((b*32 + q4)*4 + dq), 256 threads = d within quarter; q-tile 4
__global__ __launch_bounds__(256) void pv_kernel(
    const float* __restrict__ attn, const float* __restrict__ value,
    float* __restrict__ outh)
{
    __shared__ float s_a[4][512];
    const int t   = threadIdx.x;
    const int bx  = blockIdx.x;
    const int dq  = bx & 3;
    const int bq4 = bx >> 2;
    const int b   = bq4 >> 5;
    const int q4  = bq4 & 31;
    const int bq0 = b * 128 + q4 * 4;

    for (int i = t; i < 4 * 512; i += 256)
        s_a[i >> 9][i & 511] = attn[(size_t)bq0 * 512 + i];
    __syncthreads();

    const int d = dq * 256 + t;
    const float* vp = value + (size_t)b * 512 * 1024 + d;
    float c0 = 0.f, c1 = 0.f, c2 = 0.f, c3 = 0.f;
    #pragma unroll 4
    for (int k = 0; k < 512; ++k) {
        const float vv = vp[(size_t)k * 1024];           // coalesced across lanes
        c0 = __builtin_fmaf(s_a[0][k], vv, c0);
        c1 = __builtin_fmaf(s_a[1][k], vv, c1);
        c2 = __builtin_fmaf(s_a[2][k], vv, c2);
        c3 = __builtin_fmaf(s_a[3][k], vv, c3);
    }
    outh[(size_t)(bq0 + 0) * 1024 + d] = c0;
    outh[(size_t)(bq0 + 1) * 1024 + d] = c1;
    outh[(size_t)(bq0 + 2) * 1024 + d] = c2;
    outh[(size_t)(bq0 + 3) * 1024 + d] = c3;
}

extern "C" void kernel_launch(void* const* d_in, const int* in_sizes, int n_in,
                              void* d_out, int out_size, void* d_ws, size_t ws_size,
                              hipStream_t stream)
{
    const float* query = (const float*)d_in[0];
    const float* key   = (const float*)d_in[1];
    const float* value = (const float*)d_in[2];
    const float* Wq    = (const float*)d_in[3];
    const float* bq    = (const float*)d_in[4];
    const float* Wk    = (const float*)d_in[5];
    const float* v     = (const float*)d_in[6];
    float* out = (float*)d_out;

    float* ws_Ea   = (float*)d_ws;                 // 512*1024 f32   = 2 MB
    float* ws_EbT  = ws_Ea + 512 * 1024;           // 4*1024*512 f32 = 8 MB
    float* ws_part = ws_EbT + 4 * 1024 * 512;      // 512*4*512 f32  = 4 MB

    float* out_h    = out;                          // [512][1024]
    float* out_attn = out + (size_t)NB * NTQ * NH;  // [512][512]

    fused_gemm    <<<dim3(160),  dim3(256), 0, stream>>>(query, key, Wq, bq, Wk, ws_Ea, ws_EbT);
    scores_partial<<<dim3(1024), dim3(512), 0, stream>>>(ws_EbT, ws_Ea, v, ws_part);
    softmax_kernel<<<dim3(512),  dim3(512), 0, stream>>>(ws_part, out_attn);
    pv_kernel     <<<dim3(512),  dim3(256), 0, stream>>>(out_attn, value, out_h);
}

// Round 3
// 101.494 us; speedup vs baseline: 1.7441x; 1.2727x over previous
//
#include <hip/hip_runtime.h>
#include <hip/hip_bf16.h>

typedef float f32x4 __attribute__((ext_vector_type(4)));
typedef short s16x8 __attribute__((ext_vector_type(8)));
typedef short s16x4 __attribute__((ext_vector_type(4)));

#define NB  4
#define NTQ 128
#define NTK 512
#define NH  1024

__device__ __forceinline__ unsigned short f2bf(float x) {
    unsigned u = __builtin_bit_cast(unsigned, x);
    u += 0x7FFFu + ((u >> 16) & 1u);          // round-to-nearest-even
    return (unsigned short)(u >> 16);
}

#define ASTR 40   // LDS row stride in shorts (80 B)
#define K2E  2.8853900817779268f   // 2*log2(e): exp2(K2E*x) = e^{2x}

// blocks [0,32):   Ea[512][1024] = exp(2*(Q@Wq + bq))        (row-major, row = b*128+q)
// blocks [32,160): EbT[b][h][k]  = exp(2*(K@Wk)) transposed per batch
__global__ __launch_bounds__(256) void fused_gemm(
    const float* __restrict__ Q, const float* __restrict__ Kmat,
    const float* __restrict__ Wq, const float* __restrict__ bq,
    const float* __restrict__ Wk,
    float* __restrict__ Ea_out, float* __restrict__ EbT)
{
    __shared__ short As[128][ASTR];   // As[m][k] bf16 bits
    __shared__ short Bs[128][ASTR];   // Bs[n][k] bf16 bits
    const int t  = threadIdx.x;
    const int bx = blockIdx.x;
    const bool g1 = bx < 32;
    const float* A; const float* Bg; int mt, nt;
    if (g1) { A = Q;    Bg = Wq; mt = bx >> 3;        nt = bx & 7; }
    else    { A = Kmat; Bg = Wk; mt = (bx - 32) >> 3; nt = (bx - 32) & 7; }
    const int m0 = mt * 128, n0 = nt * 128;

    f32x4 acc[4][4];
    #pragma unroll
    for (int i = 0; i < 4; ++i)
        #pragma unroll
        for (int j = 0; j < 4; ++j) acc[i][j] = f32x4{0.f, 0.f, 0.f, 0.f};

    const int lane = t & 63, wid = t >> 6;
    const int wr = wid >> 1, wc = wid & 1;          // 2x2 waves, 64x64 each
    const int fr = lane & 15, fk = (lane >> 4) * 8;

    for (int k0 = 0; k0 < 1024; k0 += 32) {
        __syncthreads();
        {   // stage A tile 128x32
            const int rb = t >> 3, colg = (t & 7) * 4;
            #pragma unroll
            for (int rr = 0; rr < 4; ++rr) {
                const int row = rb + rr * 32;
                const float4 av = *(const float4*)&A[(size_t)(m0 + row) * 1024 + k0 + colg];
                s16x4 pv = { (short)f2bf(av.x), (short)f2bf(av.y),
                             (short)f2bf(av.z), (short)f2bf(av.w) };
                *(s16x4*)&As[row][colg] = pv;
            }
        }
        {   // stage B tile 32x128 -> Bs[n][k]
            const int n = t & 127, kq = (t >> 7) * 4;
            #pragma unroll
            for (int rr = 0; rr < 4; ++rr) {
                const int ks = kq + rr * 8;
                const float* bp = &Bg[(size_t)(k0 + ks) * 1024 + n0 + n];
                const float x0 = bp[0], x1 = bp[1024], x2 = bp[2048], x3 = bp[3072];
                s16x4 pv = { (short)f2bf(x0), (short)f2bf(x1),
                             (short)f2bf(x2), (short)f2bf(x3) };
                *(s16x4*)&Bs[n][ks] = pv;
            }
        }
        __syncthreads();
        s16x8 af[4], bfv[4];
        #pragma unroll
        for (int mi = 0; mi < 4; ++mi)
            af[mi] = *(const s16x8*)&As[wr * 64 + mi * 16 + fr][fk];
        #pragma unroll
        for (int ni = 0; ni < 4; ++ni)
            bfv[ni] = *(const s16x8*)&Bs[wc * 64 + ni * 16 + fr][fk];
        #pragma unroll
        for (int mi = 0; mi < 4; ++mi)
            #pragma unroll
            for (int ni = 0; ni < 4; ++ni)
                acc[mi][ni] = __builtin_amdgcn_mfma_f32_16x16x32_bf16(
                                  af[mi], bfv[ni], acc[mi][ni], 0, 0, 0);
    }

    // D layout: col = lane&15, row = (lane>>4)*4 + reg
    const int row0 = (lane >> 4) * 4;
    if (g1) {
        #pragma unroll
        for (int ni = 0; ni < 4; ++ni) {
            const int n = n0 + wc * 64 + ni * 16 + fr;
            const float bias = bq[n];
            #pragma unroll
            for (int mi = 0; mi < 4; ++mi) {
                const int m = m0 + wr * 64 + mi * 16 + row0;
                #pragma unroll
                for (int j = 0; j < 4; ++j)
                    Ea_out[(size_t)(m + j) * 1024 + n] =
                        __builtin_amdgcn_exp2f(K2E * (acc[mi][ni][j] + bias));
            }
        }
    } else {
        #pragma unroll
        for (int mi = 0; mi < 4; ++mi) {
            const int m = m0 + wr * 64 + mi * 16 + row0;
            const int b = m >> 9, kk = m & 511;
            #pragma unroll
            for (int ni = 0; ni < 4; ++ni) {
                const int n = n0 + wc * 64 + ni * 16 + fr;
                f32x4 ev;
                #pragma unroll
                for (int j = 0; j < 4; ++j)
                    ev[j] = __builtin_amdgcn_exp2f(K2E * acc[mi][ni][j]);
                *(f32x4*)&EbT[((size_t)b * 1024 + n) * 512 + kk] = ev;
            }
        }
    }
}

// scores stage: tanh(a+b) = 1 - 2/(1+Ea*Eb); the "1-" and Sum(v) cancel in softmax.
// partial[bqi][hq][k] = sum_{h in quarter} v[h] * rcp(1 + Ea[bqi][h]*Eb[b][h][k])
// grid: ((b*32+q4)*4 + hq), 512 threads = k; q-tile 4
__global__ __launch_bounds__(512) void scores_partial(
    const float* __restrict__ EbT, const float* __restrict__ Ea,
    const float* __restrict__ v, float* __restrict__ partial)
{
    __shared__ float4 s_ea[256];   // Ea rows q0..q3
    __shared__ float  s_v[256];
    const int t   = threadIdx.x;
    const int bx  = blockIdx.x;
    const int hq  = bx & 3;
    const int bq4 = bx >> 2;           // b*32 + q4
    const int b   = bq4 >> 5;
    const int q4  = bq4 & 31;
    const int bq0 = b * 128 + q4 * 4;
    const int h0  = hq * 256;

    if (t < 256) {
        const int h = h0 + t;
        s_ea[t] = make_float4(Ea[(size_t)(bq0 + 0) * 1024 + h],
                              Ea[(size_t)(bq0 + 1) * 1024 + h],
                              Ea[(size_t)(bq0 + 2) * 1024 + h],
                              Ea[(size_t)(bq0 + 3) * 1024 + h]);
        s_v[t] = v[h];
    }
    __syncthreads();

    const float* up = EbT + ((size_t)b * 1024 + h0) * 512 + t;
    float a0 = 0.f, a1 = 0.f, a2 = 0.f, a3 = 0.f;
    #pragma unroll 8
    for (int hh = 0; hh < 256; ++hh) {
        const float  eb = up[(size_t)hh * 512];          // coalesced across lanes
        const float4 ea = s_ea[hh];                      // LDS broadcast
        const float  vv = s_v[hh];
        const float r0 = __builtin_amdgcn_rcpf(__builtin_fmaf(ea.x, eb, 1.0f));
        const float r1 = __builtin_amdgcn_rcpf(__builtin_fmaf(ea.y, eb, 1.0f));
        const float r2 = __builtin_amdgcn_rcpf(__builtin_fmaf(ea.z, eb, 1.0f));
        const float r3 = __builtin_amdgcn_rcpf(__builtin_fmaf(ea.w, eb, 1.0f));
        a0 = __builtin_fmaf(vv, r0, a0);
        a1 = __builtin_fmaf(vv, r1, a1);
        a2 = __builtin_fmaf(vv, r2, a2);
        a3 = __builtin_fmaf(vv, r3, a3);
    }
    partial[((size_t)(bq0 + 0) * 4 + hq) * 512 + t] = a0;
    partial[((size_t)(bq0 + 1) * 4 + hq) * 512 + t] = a1;
    partial[((size_t)(bq0 + 2) * 4 + hq) * 512 + t] = a2;
    partial[((size_t)(bq0 + 3) * 4 + hq) * 512 + t] = a3;
}

// softmax over k: attn = softmax_k(-2 * sum_hq partial). One block per (b,q).
__global__ __launch_bounds__(512) void softmax_kernel(
    const float* __restrict__ partial, float* __restrict__ attn_out)
{
    __shared__ float s_red[16];
    const int t = threadIdx.x, bqi = blockIdx.x;
    const float* p = partial + (size_t)bqi * 2048;
    const float z = -2.0f * (p[t] + p[512 + t] + p[1024 + t] + p[1536 + t]);

    const int lane = t & 63, wid = t >> 6;
    float m = z;
    #pragma unroll
    for (int off = 32; off > 0; off >>= 1)
        m = fmaxf(m, __shfl_xor(m, off, 64));
    if (lane == 0) s_red[wid] = m;
    __syncthreads();
    if (t < 64) {
        float mm = (t < 8) ? s_red[t] : -3.0e38f;
        #pragma unroll
        for (int off = 4; off > 0; off >>= 1)
            mm = fmaxf(mm, __shfl_xor(mm, off, 64));
        if (t == 0) s_red[8] = mm;
    }
    __syncthreads();
    const float pr = __expf(z - s_red[8]);
    float s = pr;
    #pragma unroll
    for (int off = 32; off > 0; off >>= 1)
        s += __shfl_xor(s, off, 64);
    if (lane == 0) s_red[wid] = s;
    __syncthreads();
    if (t < 64) {
        float ss = (t < 8) ? s_red[t] : 0.f;
        #pragma unroll
        for (int off = 4; off > 0; off >>= 1)
            ss += __shfl_xor(ss, off, 64);
        if (t == 0) s_red[9] = ss;
    }
    __syncthreads();
    attn_out[(size_t)bqi * 512 + t] = pr * (1.0f / s_red[9]);
}

// PV as MFMA GEMM: outh[b][128 q][1024 d] = attn[b][128 q][512 k] @ value[b][512 k][1024 d]
// grid: b*8 + ntile, 256 threads, 128x128 tile, K=512
__global__ __launch_bounds__(256) void pv_gemm(
    const float* __restrict__ attn, const float* __restrict__ value,
    float* __restrict__ outh)
{
    __shared__ short As[128][ASTR];   // As[m][k]
    __shared__ short Bs[128][ASTR];   // Bs[n][k]
    const int t  = threadIdx.x;
    const int bx = blockIdx.x;
    const int b  = bx >> 3, nt = bx & 7;
    const int n0 = nt * 128;
    const float* A  = attn  + (size_t)b * 128 * 512;    // [128][512]
    const float* Bg = value + (size_t)b * 512 * 1024;   // [512][1024]

    f32x4 acc[4][4];
    #pragma unroll
    for (int i = 0; i < 4; ++i)
        #pragma unroll
        for (int j = 0; j < 4; ++j) acc[i][j] = f32x4{0.f, 0.f, 0.f, 0.f};

    const int lane = t & 63, wid = t >> 6;
    const int wr = wid >> 1, wc = wid & 1;
    const int fr = lane & 15, fk = (lane >> 4) * 8;

    for (int k0 = 0; k0 < 512; k0 += 32) {
        __syncthreads();
        {   // stage A tile 128x32 (attn rows, stride 512)
            const int rb = t >> 3, colg = (t & 7) * 4;
            #pragma unroll
            for (int rr = 0; rr < 4; ++rr) {
                const int row = rb + rr * 32;
                const float4 av = *(const float4*)&A[(size_t)row * 512 + k0 + colg];
                s16x4 pv = { (short)f2bf(av.x), (short)f2bf(av.y),
                             (short)f2bf(av.z), (short)f2bf(av.w) };
                *(s16x4*)&As[row][colg] = pv;
            }
        }
        {   // stage B tile 32x128 -> Bs[n][k] (value rows, stride 1024)
            const int n = t & 127, kq = (t >> 7) * 4;
            #pragma unroll
            for (int rr = 0; rr < 4; ++rr) {
                const int ks = kq + rr * 8;
                const float* bp = &Bg[(size_t)(k0 + ks) * 1024 + n0 + n];
                const float x0 = bp[0], x1 = bp[1024], x2 = bp[2048], x3 = bp[3072];
                s16x4 pv = { (short)f2bf(x0), (short)f2bf(x1),
                             (short)f2bf(x2), (short)f2bf(x3) };
                *(s16x4*)&Bs[n][ks] = pv;
            }
        }
        __syncthreads();
        s16x8 af[4], bfv[4];
        #pragma unroll
        for (int mi = 0; mi < 4; ++mi)
            af[mi] = *(const s16x8*)&As[wr * 64 + mi * 16 + fr][fk];
        #pragma unroll
        for (int ni = 0; ni < 4; ++ni)
            bfv[ni] = *(const s16x8*)&Bs[wc * 64 + ni * 16 + fr][fk];
        #pragma unroll
        for (int mi = 0; mi < 4; ++mi)
            #pragma unroll
            for (int ni = 0; ni < 4; ++ni)
                acc[mi][ni] = __builtin_amdgcn_mfma_f32_16x16x32_bf16(
                                  af[mi], bfv[ni], acc[mi][ni], 0, 0, 0);
    }

    const int row0 = (lane >> 4) * 4;
    #pragma unroll
    for (int ni = 0; ni < 4; ++ni) {
        const int n = n0 + wc * 64 + ni * 16 + fr;
        #pragma unroll
        for (int mi = 0; mi < 4; ++mi) {
            const int m = wr * 64 + mi * 16 + row0;
            #pragma unroll
            for (int j = 0; j < 4; ++j)
                outh[(size_t)(b * 128 + m + j) * 1024 + n] = acc[mi][ni][j];
        }
    }
}

extern "C" void kernel_launch(void* const* d_in, const int* in_sizes, int n_in,
                              void* d_out, int out_size, void* d_ws, size_t ws_size,
                              hipStream_t stream)
{
    const float* query = (const float*)d_in[0];
    const float* key   = (const float*)d_in[1];
    const float* value = (const float*)d_in[2];
    const float* Wq    = (const float*)d_in[3];
    const float* bq    = (const float*)d_in[4];
    const float* Wk    = (const float*)d_in[5];
    const float* v     = (const float*)d_in[6];
    float* out = (float*)d_out;

    float* ws_Ea   = (float*)d_ws;                 // 512*1024 f32   = 2 MB
    float* ws_EbT  = ws_Ea + 512 * 1024;           // 4*1024*512 f32 = 8 MB
    float* ws_part = ws_EbT + 4 * 1024 * 512;      // 512*4*512 f32  = 4 MB

    float* out_h    = out;                          // [512][1024]
    float* out_attn = out + (size_t)NB * NTQ * NH;  // [512][512]

    fused_gemm    <<<dim3(160), dim3(256), 0, stream>>>(query, key, Wq, bq, Wk, ws_Ea, ws_EbT);
    scores_partial<<<dim3(512), dim3(512), 0, stream>>>(ws_EbT, ws_Ea, v, ws_part);
    softmax_kernel<<<dim3(512), dim3(512), 0, stream>>>(ws_part, out_attn);
    pv_gemm       <<<dim3(32),  dim3(256), 0, stream>>>(out_attn, value, out_h);
}

// Round 4
// 75.817 us; speedup vs baseline: 2.3347x; 1.3387x over previous
//
#include <hip/hip_runtime.h>
#include <hip/hip_bf16.h>

typedef float f32x4 __attribute__((ext_vector_type(4)));
typedef short s16x8 __attribute__((ext_vector_type(8)));
typedef short s16x4 __attribute__((ext_vector_type(4)));

#define NB  4
#define NTQ 128
#define NTK 512
#define NH  1024

__device__ __forceinline__ unsigned short f2bf(float x) {
    unsigned u = __builtin_bit_cast(unsigned, x);
    u += 0x7FFFu + ((u >> 16) & 1u);          // round-to-nearest-even
    return (unsigned short)(u >> 16);
}

#define K2E  2.8853900817779268f   // 2*log2(e): exp2(K2E*x) = e^{2x}

// async global->LDS 16B: linear LDS dest (wave base + lane*16), per-lane global src
#define GLD16(gp, lp) __builtin_amdgcn_global_load_lds( \
    (const __attribute__((address_space(1))) unsigned int*)(gp), \
    (__attribute__((address_space(3))) unsigned int*)(lp), 16, 0, 0)

// ---------------------------------------------------------------------------
// prep: bf16 convert Q,K; transpose-convert Wq,Wk -> [n][k]; value -> [b][d][k]
// blocks: [0,512) Q | [512,2560) K | [2560,3584) Wq | [3584,4608) Wk | [4608,6656) value
__global__ __launch_bounds__(256) void prep_kernel(
    const float* __restrict__ Q, const float* __restrict__ K,
    const float* __restrict__ Wq, const float* __restrict__ Wk,
    const float* __restrict__ value,
    short* __restrict__ Qb, short* __restrict__ Kb,
    short* __restrict__ WqT, short* __restrict__ WkT, short* __restrict__ valT)
{
    const int t = threadIdx.x, bx = blockIdx.x;
    if (bx < 2560) {
        const float* src; short* dst; size_t off;
        if (bx < 512) { src = Q; dst = Qb; off = (size_t)bx * 1024 + t * 4; }
        else          { src = K; dst = Kb; off = (size_t)(bx - 512) * 1024 + t * 4; }
        const float4 vv = *(const float4*)(src + off);
        s16x4 o = { (short)f2bf(vv.x), (short)f2bf(vv.y),
                    (short)f2bf(vv.z), (short)f2bf(vv.w) };
        *(s16x4*)(dst + off) = o;
        return;
    }
    __shared__ float tile[32][33];
    const float* src; short* dst; int R, C, r0, c0;
    if (bx < 3584)      { const int i = bx - 2560; src = Wq; dst = WqT; C = 1024; R = 1024; r0 = (i >> 5) * 32; c0 = (i & 31) * 32; }
    else if (bx < 4608) { const int i = bx - 3584; src = Wk; dst = WkT; C = 1024; R = 1024; r0 = (i >> 5) * 32; c0 = (i & 31) * 32; }
    else {
        const int i = bx - 4608, b = i >> 9, rr = i & 511;
        src = value + (size_t)b * 512 * 1024; dst = valT + (size_t)b * 1024 * 512;
        C = 1024; R = 512; r0 = (rr >> 5) * 32; c0 = (rr & 31) * 32;
    }
    const int lr = t >> 3, lc = (t & 7) * 4;
    {
        const float4 vv = *(const float4*)(src + (size_t)(r0 + lr) * C + c0 + lc);
        tile[lr][lc + 0] = vv.x; tile[lr][lc + 1] = vv.y;
        tile[lr][lc + 2] = vv.z; tile[lr][lc + 3] = vv.w;
    }
    __syncthreads();
    s16x4 o = { (short)f2bf(tile[lc + 0][lr]), (short)f2bf(tile[lc + 1][lr]),
                (short)f2bf(tile[lc + 2][lr]), (short)f2bf(tile[lc + 3][lr]) };
    *(s16x4*)(dst + (size_t)(c0 + lr) * R + r0 + lc) = o;
}

// ---------------------------------------------------------------------------
// main GEMMs with epilogue exp: blocks [0,32): Ea = exp(2*(Q@Wq+bq));
// blocks [32,160): EbT[b][h][k] = exp(2*(K@Wk)) transposed.
// 128x128 tile, BK=64, dbuf LDS via global_load_lds, XOR-swizzled (T2 rule #21).
__global__ __launch_bounds__(256) void mm_kernel(
    const short* __restrict__ Qb, const short* __restrict__ Kb,
    const short* __restrict__ WqT, const short* __restrict__ WkT,
    const float* __restrict__ bq,
    float* __restrict__ Ea_out, float* __restrict__ EbT)
{
    __shared__ short lds[2][2][128][64];   // 64 KB: [buf][A/B][row][k]
    const int t = threadIdx.x, bx = blockIdx.x;
    const bool g1 = bx < 32;
    const short *A, *B; int m0, n0;
    if (g1) { A = Qb; B = WqT; m0 = (bx >> 3) * 128;        n0 = (bx & 7) * 128; }
    else    { const int i = bx - 32; A = Kb; B = WkT; m0 = (i >> 3) * 128; n0 = (i & 7) * 128; }
    A += (size_t)m0 * 1024; B += (size_t)n0 * 1024;

    f32x4 acc[4][4];
    #pragma unroll
    for (int i = 0; i < 4; ++i)
        #pragma unroll
        for (int j = 0; j < 4; ++j) acc[i][j] = f32x4{0.f, 0.f, 0.f, 0.f};

    const int lane = t & 63, wid = t >> 6;
    const int wr = wid >> 1, wc = wid & 1;
    const int fr = lane & 15, fko = (lane >> 4) * 16;   // byte offset in 128B row

    // stage both 128x64 tiles: idx in [0,1024), row=idx>>3, chunk=idx&7; src pre-swizzled
    #define STAGE_MM(buf, k0) do {                                              \
        _Pragma("unroll")                                                       \
        for (int it = 0; it < 4; ++it) {                                        \
            const int idx = it * 256 + t;                                       \
            const int row = idx >> 3, c16 = idx & 7;                            \
            const int sc = c16 ^ (row & 7);                                     \
            GLD16(A + (size_t)row * 1024 + (k0) + sc * 8,                       \
                  &lds[buf][0][0][0] + idx * 8);                                \
            GLD16(B + (size_t)row * 1024 + (k0) + sc * 8,                       \
                  &lds[buf][1][0][0] + idx * 8);                                \
        }                                                                       \
    } while (0)

    #define COMPUTE_MM(buf) do {                                                \
        _Pragma("unroll")                                                       \
        for (int kk = 0; kk < 2; ++kk) {                                        \
            s16x8 af[4], bfv[4];                                                \
            _Pragma("unroll")                                                   \
            for (int i = 0; i < 4; ++i) {                                       \
                const int rowA = wr * 64 + i * 16 + fr;                         \
                int offA = rowA * 128 + kk * 64 + fko; offA ^= (rowA & 7) << 4; \
                af[i] = *(const s16x8*)((const char*)&lds[buf][0][0][0] + offA);\
                const int rowB = wc * 64 + i * 16 + fr;                         \
                int offB = rowB * 128 + kk * 64 + fko; offB ^= (rowB & 7) << 4; \
                bfv[i] = *(const s16x8*)((const char*)&lds[buf][1][0][0] + offB);\
            }                                                                   \
            _Pragma("unroll")                                                   \
            for (int mi = 0; mi < 4; ++mi)                                      \
                _Pragma("unroll")                                               \
                for (int ni = 0; ni < 4; ++ni)                                  \
                    acc[mi][ni] = __builtin_amdgcn_mfma_f32_16x16x32_bf16(      \
                                      af[mi], bfv[ni], acc[mi][ni], 0, 0, 0);   \
        }                                                                       \
    } while (0)

    STAGE_MM(0, 0);
    __syncthreads();
    int cur = 0;
    for (int s = 0; s < 15; ++s) {
        STAGE_MM(cur ^ 1, (s + 1) * 64);
        COMPUTE_MM(cur);
        __syncthreads();
        cur ^= 1;
    }
    COMPUTE_MM(cur);

    // D layout: col = lane&15, row = (lane>>4)*4 + reg
    const int row0 = (lane >> 4) * 4;
    if (g1) {
        #pragma unroll
        for (int ni = 0; ni < 4; ++ni) {
            const int n = n0 + wc * 64 + ni * 16 + fr;
            const float bias = bq[n];
            #pragma unroll
            for (int mi = 0; mi < 4; ++mi) {
                const int m = m0 + wr * 64 + mi * 16 + row0;
                #pragma unroll
                for (int j = 0; j < 4; ++j)
                    Ea_out[(size_t)(m + j) * 1024 + n] =
                        __builtin_amdgcn_exp2f(K2E * (acc[mi][ni][j] + bias));
            }
        }
    } else {
        #pragma unroll
        for (int mi = 0; mi < 4; ++mi) {
            const int m = m0 + wr * 64 + mi * 16 + row0;
            const int b = m >> 9, kk = m & 511;
            #pragma unroll
            for (int ni = 0; ni < 4; ++ni) {
                const int n = n0 + wc * 64 + ni * 16 + fr;
                f32x4 ev;
                #pragma unroll
                for (int j = 0; j < 4; ++j)
                    ev[j] = __builtin_amdgcn_exp2f(K2E * acc[mi][ni][j]);
                *(f32x4*)&EbT[((size_t)b * 1024 + n) * 512 + kk] = ev;
            }
        }
    }
    #undef STAGE_MM
    #undef COMPUTE_MM
}

// ---------------------------------------------------------------------------
// scores: partial[bqi][hc][k] = sum_{h in chunk} v[h]*rcp(1+Ea[bqi][h]*Eb[b][h][k])
// grid: (b*16+q8)*8 + hc; q-tile 8, h-chunk 128; 512 threads = k
__global__ __launch_bounds__(512) void scores_partial(
    const float* __restrict__ EbT, const float* __restrict__ Ea,
    const float* __restrict__ v, float* __restrict__ partial)
{
    __shared__ float s_ea[128][8];
    __shared__ float s_v[128];
    const int t = threadIdx.x, bx = blockIdx.x;
    const int hc = bx & 7, bq8 = bx >> 3;
    const int b = bq8 >> 4, q8 = bq8 & 15;
    const int bq0 = b * 128 + q8 * 8, h0 = hc * 128;

    if (t < 128) {
        #pragma unroll
        for (int q = 0; q < 8; ++q)
            s_ea[t][q] = Ea[(size_t)(bq0 + q) * 1024 + h0 + t];
        s_v[t] = v[h0 + t];
    }
    __syncthreads();

    const float* up = EbT + ((size_t)b * 1024 + h0) * 512 + t;
    float a[8] = {0.f, 0.f, 0.f, 0.f, 0.f, 0.f, 0.f, 0.f};
    #pragma unroll 4
    for (int hh = 0; hh < 128; ++hh) {
        const float eb = up[(size_t)hh * 512];   // coalesced across lanes
        const float vv = s_v[hh];
        #pragma unroll
        for (int q = 0; q < 8; ++q) {
            const float r = __builtin_amdgcn_rcpf(__builtin_fmaf(s_ea[hh][q], eb, 1.0f));
            a[q] = __builtin_fmaf(vv, r, a[q]);
        }
    }
    #pragma unroll
    for (int q = 0; q < 8; ++q)
        partial[((size_t)(bq0 + q) * 8 + hc) * 512 + t] = a[q];
}

// softmax over k of -2*sum_hc partial; writes f32 attn (output) + bf16 copy (for PV)
__global__ __launch_bounds__(512) void softmax_kernel(
    const float* __restrict__ partial, float* __restrict__ attn_out,
    short* __restrict__ attnb)
{
    __shared__ float s_red[16];
    const int t = threadIdx.x, bqi = blockIdx.x;
    const float* p = partial + (size_t)bqi * 4096;
    float zs = 0.f;
    #pragma unroll
    for (int j = 0; j < 8; ++j) zs += p[j * 512 + t];
    const float z = -2.0f * zs;

    const int lane = t & 63, wid = t >> 6;
    float m = z;
    #pragma unroll
    for (int off = 32; off > 0; off >>= 1)
        m = fmaxf(m, __shfl_xor(m, off, 64));
    if (lane == 0) s_red[wid] = m;
    __syncthreads();
    if (t < 64) {
        float mm = (t < 8) ? s_red[t] : -3.0e38f;
        #pragma unroll
        for (int off = 4; off > 0; off >>= 1)
            mm = fmaxf(mm, __shfl_xor(mm, off, 64));
        if (t == 0) s_red[8] = mm;
    }
    __syncthreads();
    const float pr = __expf(z - s_red[8]);
    float s = pr;
    #pragma unroll
    for (int off = 32; off > 0; off >>= 1)
        s += __shfl_xor(s, off, 64);
    if (lane == 0) s_red[wid] = s;
    __syncthreads();
    if (t < 64) {
        float ss = (t < 8) ? s_red[t] : 0.f;
        #pragma unroll
        for (int off = 4; off > 0; off >>= 1)
            ss += __shfl_xor(ss, off, 64);
        if (t == 0) s_red[9] = ss;
    }
    __syncthreads();
    const float attn = pr * (1.0f / s_red[9]);
    attn_out[(size_t)bqi * 512 + t] = attn;
    attnb[(size_t)bqi * 512 + t] = (short)f2bf(attn);
}

// ---------------------------------------------------------------------------
// PV GEMM: outh[b][128][1024] = attnb[b][128][512] @ valT[b][1024][512]^T
// same structure as mm_kernel, K=512 (8 steps); grid b*8+nt
__global__ __launch_bounds__(256) void pv_gemm(
    const short* __restrict__ attnb, const short* __restrict__ valT,
    float* __restrict__ outh)
{
    __shared__ short lds[2][2][128][64];
    const int t = threadIdx.x, bx = blockIdx.x;
    const int b = bx >> 3, nt = bx & 7;
    const int n0 = nt * 128;
    const short* A = attnb + (size_t)b * 128 * 512;          // [128][512]
    const short* B = valT + (size_t)b * 1024 * 512 + (size_t)n0 * 512;  // [128][512] tile

    f32x4 acc[4][4];
    #pragma unroll
    for (int i = 0; i < 4; ++i)
        #pragma unroll
        for (int j = 0; j < 4; ++j) acc[i][j] = f32x4{0.f, 0.f, 0.f, 0.f};

    const int lane = t & 63, wid = t >> 6;
    const int wr = wid >> 1, wc = wid & 1;
    const int fr = lane & 15, fko = (lane >> 4) * 16;

    #define STAGE_PV(buf, k0) do {                                              \
        _Pragma("unroll")                                                       \
        for (int it = 0; it < 4; ++it) {                                        \
            const int idx = it * 256 + t;                                       \
            const int row = idx >> 3, c16 = idx & 7;                            \
            const int sc = c16 ^ (row & 7);                                     \
            GLD16(A + (size_t)row * 512 + (k0) + sc * 8,                        \
                  &lds[buf][0][0][0] + idx * 8);                                \
            GLD16(B + (size_t)row * 512 + (k0) + sc * 8,                        \
                  &lds[buf][1][0][0] + idx * 8);                                \
        }                                                                       \
    } while (0)

    #define COMPUTE_PV(buf) do {                                                \
        _Pragma("unroll")                                                       \
        for (int kk = 0; kk < 2; ++kk) {                                        \
            s16x8 af[4], bfv[4];                                                \
            _Pragma("unroll")                                                   \
            for (int i = 0; i < 4; ++i) {                                       \
                const int rowA = wr * 64 + i * 16 + fr;                         \
                int offA = rowA * 128 + kk * 64 + fko; offA ^= (rowA & 7) << 4; \
                af[i] = *(const s16x8*)((const char*)&lds[buf][0][0][0] + offA);\
                const int rowB = wc * 64 + i * 16 + fr;                         \
                int offB = rowB * 128 + kk * 64 + fko; offB ^= (rowB & 7) << 4; \
                bfv[i] = *(const s16x8*)((const char*)&lds[buf][1][0][0] + offB);\
            }                                                                   \
            _Pragma("unroll")                                                   \
            for (int mi = 0; mi < 4; ++mi)                                      \
                _Pragma("unroll")                                               \
                for (int ni = 0; ni < 4; ++ni)                                  \
                    acc[mi][ni] = __builtin_amdgcn_mfma_f32_16x16x32_bf16(      \
                                      af[mi], bfv[ni], acc[mi][ni], 0, 0, 0);   \
        }                                                                       \
    } while (0)

    STAGE_PV(0, 0);
    __syncthreads();
    int cur = 0;
    for (int s = 0; s < 7; ++s) {
        STAGE_PV(cur ^ 1, (s + 1) * 64);
        COMPUTE_PV(cur);
        __syncthreads();
        cur ^= 1;
    }
    COMPUTE_PV(cur);

    const int row0 = (lane >> 4) * 4;
    #pragma unroll
    for (int ni = 0; ni < 4; ++ni) {
        const int n = n0 + wc * 64 + ni * 16 + fr;
        #pragma unroll
        for (int mi = 0; mi < 4; ++mi) {
            const int m = wr * 64 + mi * 16 + row0;
            #pragma unroll
            for (int j = 0; j < 4; ++j)
                outh[(size_t)(b * 128 + m + j) * 1024 + n] = acc[mi][ni][j];
        }
    }
    #undef STAGE_PV
    #undef COMPUTE_PV
}

extern "C" void kernel_launch(void* const* d_in, const int* in_sizes, int n_in,
                              void* d_out, int out_size, void* d_ws, size_t ws_size,
                              hipStream_t stream)
{
    const float* query = (const float*)d_in[0];
    const float* key   = (const float*)d_in[1];
    const float* value = (const float*)d_in[2];
    const float* Wq    = (const float*)d_in[3];
    const float* bq    = (const float*)d_in[4];
    const float* Wk    = (const float*)d_in[5];
    const float* v     = (const float*)d_in[6];
    float* out = (float*)d_out;

    // workspace layout (23.5 MB):
    char* w = (char*)d_ws;
    float* ws_Ea  = (float*)w;                            // 2 MB
    float* ws_EbT = (float*)(w + (2u << 20));             // 8 MB
    char*  reg    = w + (10u << 20);                      // 9 MB shared region
    short* Qb   = (short*)reg;                            //   1 MB
    short* Kb   = (short*)(reg + (1u << 20));             //   4 MB
    short* WqT  = (short*)(reg + (5u << 20));             //   2 MB
    short* WkT  = (short*)(reg + (7u << 20));             //   2 MB
    float* part = (float*)reg;                            //   8 MB (aliases; Qb..WkT dead after mm)
    short* valT  = (short*)(w + (19u << 20));             // 4 MB
    short* attnb = (short*)(w + (23u << 20));             // 0.5 MB

    float* out_h    = out;                                // [512][1024]
    float* out_attn = out + (size_t)NB * NTQ * NH;        // [512][512]

    prep_kernel   <<<dim3(6656), dim3(256), 0, stream>>>(query, key, Wq, Wk, value,
                                                         Qb, Kb, WqT, WkT, valT);
    mm_kernel     <<<dim3(160),  dim3(256), 0, stream>>>(Qb, Kb, WqT, WkT, bq, ws_Ea, ws_EbT);
    scores_partial<<<dim3(512),  dim3(512), 0, stream>>>(ws_EbT, ws_Ea, v, part);
    softmax_kernel<<<dim3(512),  dim3(512), 0, stream>>>(part, out_attn, attnb);
    pv_gemm       <<<dim3(32),   dim3(256), 0, stream>>>(attnb, valT, out_h);
}